// Round 17
// baseline (96.340 us; speedup 1.0000x reference)
//
#include <hip/hip_runtime.h>
#include <hip/hip_bf16.h>

#define CCH 512
#define TTT 1024
#define BBB 8
#define NGRP 32
#define CPG 16
#define NHEAD 8
#define CHD 64
#define O_QKV 1536

typedef __attribute__((ext_vector_type(8))) short bf16x8;
typedef __attribute__((ext_vector_type(4))) short s16x4;
typedef __attribute__((ext_vector_type(8))) unsigned short u16x8;
typedef __attribute__((ext_vector_type(4))) float f32x4;

__device__ __forceinline__ float us2f(unsigned short u) {
  union { unsigned int i; float f; } p; p.i = ((unsigned int)u) << 16; return p.f;
}
__device__ __forceinline__ unsigned short f2us(float f) {
  __hip_bfloat16 b = __float2bfloat16(f);
  return *reinterpret_cast<unsigned short*>(&b);
}
__device__ __forceinline__ bf16x8 cat8(s16x4 a, s16x4 b) {
  bf16x8 r;
  r[0] = a[0]; r[1] = a[1]; r[2] = a[2]; r[3] = a[3];
  r[4] = b[0]; r[5] = b[1]; r[6] = b[2]; r[7] = b[3];
  return r;
}
__device__ __forceinline__ float hmax4(f32x4 v) {
  return fmaxf(fmaxf(v[0], v[1]), fmaxf(v[2], v[3]));
}
__device__ __forceinline__ unsigned int pk2(float lo, float hi) {
  return ((unsigned int)f2us(hi) << 16) | (unsigned int)f2us(lo);
}

// OLD packed layout (hP, W, avP): subtile base (rt*(K/16)+kt)*256,
// within: ((k%16)/4)*64 + (row%16)*4 + (k%4).
// PL2 layout (qP, kP, vP): same subtile order, within row-major:
// (row%16)*16 + (k%16). Frag = ONE b128.

// ---------------- W f32 -> packed bf16 (old layout, unchanged) ----------------
__global__ __launch_bounds__(256) void wpack_kernel(
    const float* __restrict__ wq, const float* __restrict__ wp,
    unsigned short* __restrict__ op, int nslot)
{
  const int s = blockIdx.x * 256 + threadIdx.x;
  if (s >= nslot) return;
  const int u = s & 63, sub = s >> 6;
  const int kt = sub & 31, rt = sub >> 5;
  const int lg = u >> 4, lr = u & 15;
  const int row = rt * 16 + lr;
  const float* src = (row < O_QKV) ? &wq[(size_t)row * CCH]
                                   : &wp[(size_t)(row - O_QKV) * CCH];
  float4 v = *reinterpret_cast<const float4*>(&src[kt * 16 + lg * 4]);
  ushort4 r;
  r.x = f2us(v.x); r.y = f2us(v.y); r.z = f2us(v.z); r.w = f2us(v.w);
  reinterpret_cast<ushort4*>(op)[s] = r;
}

// ---------------- GroupNorm (old hP layout, unchanged) ----------------
__global__ __launch_bounds__(256) void gn_kernel(
    const float* __restrict__ x,
    const float* __restrict__ gw,
    const float* __restrict__ gb,
    unsigned short* __restrict__ hP)
{
  __shared__ __align__(16) float xs[16][1028];
  const int bg = blockIdx.x;
  const int bb = bg >> 5, g = bg & 31;
  const size_t base = ((size_t)bb * CCH + (size_t)g * CPG) * TTT;
  const float4* xv = reinterpret_cast<const float4*>(x + base);
  const int tid = threadIdx.x;

  float s = 0.f, q = 0.f;
  for (int i = tid; i < 4096; i += 256) {
    float4 u = xv[i];
    const int c = i >> 8, t4 = (i & 255) << 2;
    *reinterpret_cast<float4*>(&xs[c][t4]) = u;
    s += (u.x + u.y) + (u.z + u.w);
    q += u.x * u.x + u.y * u.y + u.z * u.z + u.w * u.w;
  }
  #pragma unroll
  for (int off = 32; off > 0; off >>= 1) {
    s += __shfl_down(s, off);
    q += __shfl_down(q, off);
  }
  __shared__ float red[10];
  const int wid = tid >> 6, lane = tid & 63;
  if (lane == 0) { red[wid] = s; red[4 + wid] = q; }
  __syncthreads();
  if (tid == 0) {
    float S = red[0] + red[1] + red[2] + red[3];
    float Q = red[4] + red[5] + red[6] + red[7];
    float mu = S * (1.f / 16384.f);
    float var = Q * (1.f / 16384.f) - mu * mu;
    red[8] = mu;
    red[9] = rsqrtf(var + 1e-5f);
  }
  __syncthreads();
  const float mu = red[8], rstd = red[9];
  float wsc[16], wbs[16];
  #pragma unroll
  for (int cc = 0; cc < 16; cc++) {
    wsc[cc] = gw[g * CPG + cc] * rstd;
    wbs[cc] = gb[g * CPG + cc] - mu * wsc[cc];
  }
  for (int tt = tid; tt < 1024; tt += 256) {
    float v[16];
    #pragma unroll
    for (int cc = 0; cc < 16; cc++)
      v[cc] = fmaf(xs[cc][tt], wsc[cc], wbs[cc]);
    unsigned short* dst = &hP[(size_t)bb * 524288 + ((size_t)((tt >> 4) * 32 + g)) * 256 + (tt & 15) * 4];
    #pragma unroll
    for (int l2 = 0; l2 < 4; l2++) {
      ushort4 st;
      st.x = f2us(v[l2 * 4 + 0]);
      st.y = f2us(v[l2 * 4 + 1]);
      st.z = f2us(v[l2 * 4 + 2]);
      st.w = f2us(v[l2 * 4 + 3]);
      *reinterpret_cast<ushort4*>(&dst[l2 * 64]) = st;
    }
  }
}

// ---------------- LDS-free packed MFMA GEMM, reg-dbuf K loop (R14 grids) ----------------
template<int MODE>
__global__ __launch_bounds__(256) void gemm_p(
    const unsigned short* __restrict__ Ap,
    const unsigned short* __restrict__ Bp,
    const float* __restrict__ bias,
    const float* __restrict__ resid,
    unsigned short* __restrict__ oq,
    unsigned short* __restrict__ ok,
    unsigned short* __restrict__ ov,
    float* __restrict__ of,
    const int O)
{
  const int tid = threadIdx.x;
  const int bz = blockIdx.z, o0 = blockIdx.y << 7, t0 = blockIdx.x << 7;
  const int lane = tid & 63, w = tid >> 6;
  const int lg = lane >> 4, lr = lane & 15;
  const int wr = w >> 1, wc = w & 1;
  const int laneoff = (lg >> 1) * 256 + (lg & 1) * 128 + lr * 4;

  const unsigned short* Ab = Ap + (size_t)(((o0 >> 4) + wr * 4) * 32) * 256 + laneoff;
  const unsigned short* Bb = Bp + (size_t)bz * 524288
      + (size_t)(((t0 >> 4) + wc * 4) * 32) * 256 + laneoff;

  f32x4 acc[4][4];
  #pragma unroll
  for (int m = 0; m < 4; m++)
    #pragma unroll
    for (int n = 0; n < 4; n++) acc[m][n] = f32x4{0.f, 0.f, 0.f, 0.f};

#define LOADSET(af_, bf_, kb_) do {                                        \
    _Pragma("unroll") for (int m_ = 0; m_ < 4; m_++) {                     \
      const unsigned short* p_ = Ab + (m_ * 32 + (kb_)) * 256;             \
      af_[m_] = cat8(*reinterpret_cast<const s16x4*>(p_),                  \
                     *reinterpret_cast<const s16x4*>(p_ + 64));            \
    }                                                                      \
    _Pragma("unroll") for (int n_ = 0; n_ < 4; n_++) {                     \
      const unsigned short* p_ = Bb + (n_ * 32 + (kb_)) * 256;             \
      bf_[n_] = cat8(*reinterpret_cast<const s16x4*>(p_),                  \
                     *reinterpret_cast<const s16x4*>(p_ + 64));            \
    } } while (0)

#define MFMASET(af_, bf_) do {                                             \
    __builtin_amdgcn_s_setprio(1);                                         \
    _Pragma("unroll") for (int n_ = 0; n_ < 4; n_++)                       \
      _Pragma("unroll") for (int m_ = 0; m_ < 4; m_++)                     \
        acc[m_][n_] = __builtin_amdgcn_mfma_f32_16x16x32_bf16(             \
            af_[m_], bf_[n_], acc[m_][n_], 0, 0, 0);                       \
    __builtin_amdgcn_s_setprio(0); } while (0)

  bf16x8 afA[4], bfA[4], afB[4], bfB[4];
  LOADSET(afA, bfA, 0);
  #pragma unroll
  for (int kb = 0; kb < 32; kb += 4) {
    LOADSET(afB, bfB, kb + 2);          // prefetch next half-step
    MFMASET(afA, bfA);
    if (kb + 4 < 32) LOADSET(afA, bfA, kb + 4);
    MFMASET(afB, bfB);
  }
#undef LOADSET
#undef MFMASET

  if (MODE == 0) {
    const int a = (o0 >> 6) + wr;
    float bi[4][4];
    #pragma unroll
    for (int m = 0; m < 4; m++)
      #pragma unroll
      for (int r = 0; r < 4; r++)
        bi[m][r] = bias[a * 64 + m * 16 + lg * 4 + r];
    const int head = a / 3, part = a - head * 3;
    const size_t bho = ((size_t)bz * NHEAD + head) << 16;
    if (part < 2) {
      unsigned short* dst = (part == 0 ? oq : ok) + bho;
      #pragma unroll
      for (int n = 0; n < 4; n++) {
        const int rt = (t0 >> 4) + wc * 4 + n;
        #pragma unroll
        for (int m = 0; m < 4; m++) {
          ushort4 st;
          st.x = f2us(acc[m][n][0] + bi[m][0]);
          st.y = f2us(acc[m][n][1] + bi[m][1]);
          st.z = f2us(acc[m][n][2] + bi[m][2]);
          st.w = f2us(acc[m][n][3] + bi[m][3]);
          *reinterpret_cast<ushort4*>(&dst[(size_t)(rt * 4 + m) * 256 + lr * 16 + lg * 4]) = st;
        }
      }
    } else {
      unsigned short* dst = ov + bho;
      #pragma unroll
      for (int m = 0; m < 4; m++)
        #pragma unroll
        for (int n = 0; n < 4; n++) {
          const int kt = (t0 >> 4) + wc * 4 + n;
          unsigned short* q = &dst[(size_t)(m * 64 + kt) * 256 + lr];
          #pragma unroll
          for (int r = 0; r < 4; r++)
            q[(lg * 4 + r) * 16] = f2us(acc[m][n][r] + bi[m][r]);
        }
    }
  } else {
    #pragma unroll
    for (int m = 0; m < 4; m++)
      #pragma unroll
      for (int r = 0; r < 4; r++) {
        const int o = o0 + wr * 64 + m * 16 + lg * 4 + r;
        const float bv = bias[o];
        const size_t rowbase = ((size_t)bz * O + o) * TTT + t0 + wc * 64 + lr;
        #pragma unroll
        for (int n = 0; n < 4; n++) {
          const size_t idx = rowbase + n * 16;
          of[idx] = acc[m][n][r] + bv + resid[idx];
        }
      }
  }
}

// ---------------- LDS-staged flash attention: 16 q/wave, grid 1024 ----------------
// 512-thread blocks, 8 waves = 4 qg (16-query subtile each) x 2 sh (s-halves).
// Half the work per wave vs R15 -> 8192 waves total = 32/CU nominal (if VGPR<=64).
// Staging (per block, full 64-s K/V tile) byte-identical to R15.
__global__ __launch_bounds__(512, 4) void attn_p(
    const unsigned short* __restrict__ qP,
    const unsigned short* __restrict__ kP,
    const unsigned short* __restrict__ vP,
    unsigned short* __restrict__ avP)
{
  const int bid = blockIdx.x;                    // 0..1023
  const int bh = (bid & 7) * 8 + ((bid >> 3) & 7);  // all 16 t-blocks of bh: same XCD
  const int t0 = (bid >> 6) << 6;                // 16 t-blocks of 64 queries
  const int b = bh >> 3, hh = bh & 7;
  const int tid = threadIdx.x;
  const int lane = tid & 63, w = tid >> 6;       // 8 waves
  const int qg = w & 3, sh = w >> 2;             // query 16-group, s-half
  const int lg = lane >> 4, lr = lane & 15;

  // kv (32 KB, main loop) and mrg (19.5 KB, epilogue only) alias one buffer.
  __shared__ __align__(16) unsigned char smem[32768];
  unsigned short (*kv)[2][4096] = reinterpret_cast<unsigned short (*)[2][4096]>(smem);
  float (*mrg)[64][19] = reinterpret_cast<float (*)[64][19]>(smem);

  const unsigned short* Qb = qP + ((size_t)bh << 16);
  const unsigned short* Kb = kP + ((size_t)bh << 16);
  const unsigned short* Vb = vP + ((size_t)bh << 16);

  // staging: thread = one 16B unit of K and one of V per tile (== R15)
  const int p = tid;
  const int swp8 = (p ^ ((p >> 4) & 1)) * 8;
  const int vsrc0 = ((p >> 7) * 64 + ((p >> 5) & 3)) * 256 + (p & 31) * 8;

  const int PLOFF = (lg >> 1) * 256 + lr * 16 + (lg & 1) * 8;
  const int hK = (lg & 1) ^ ((lr >> 2) & 1);
  const int hV = (lg & 1) ^ ((lr >> 3) & 1);
  int koff[2];
  #pragma unroll
  for (int sn = 0; sn < 2; sn++) {
    const int srow4 = (sh * 2 + (lr >> 3)) * 4 + (lg >> 1);
    const int row16 = ((lr >> 2) & 1) * 8 + sn * 4 + (lr & 3);
    koff[sn] = srow4 * 256 + row16 * 16 + hK * 8;
  }
  const int voffb = (sh * 2 + (lg >> 1)) * 256 + lr * 16 + hV * 8;

  const int rt = (t0 >> 4) + qg;                 // this wave's query subtile
  const bf16x8 aq0 = *reinterpret_cast<const bf16x8*>(&Qb[rt * 1024 + PLOFF]);
  const bf16x8 aq1 = *reinterpret_cast<const bf16x8*>(&Qb[rt * 1024 + 512 + PLOFF]);

  f32x4 opv[4];
  #pragma unroll
  for (int cn = 0; cn < 4; cn++) opv[cn] = f32x4{0.f, 0.f, 0.f, 0.f};
  float mrow = -1e30f, lrow = 0.f;
  const float SC2 = 0.125f * 1.44269504f;

  u16x8 rK = *reinterpret_cast<const u16x8*>(&Kb[p * 8]);
  u16x8 rV = *reinterpret_cast<const u16x8*>(&Vb[vsrc0]);
  *reinterpret_cast<u16x8*>(&kv[0][0][swp8]) = rK;
  *reinterpret_cast<u16x8*>(&kv[0][1][swp8]) = rV;
  rK = *reinterpret_cast<const u16x8*>(&Kb[4096 + p * 8]);
  rV = *reinterpret_cast<const u16x8*>(&Vb[1024 + vsrc0]);

  for (int T = 0; T < 16; T++) {
    const int buf = T & 1;
    __syncthreads();
    if (T + 1 < 16) {
      *reinterpret_cast<u16x8*>(&kv[buf ^ 1][0][swp8]) = rK;
      *reinterpret_cast<u16x8*>(&kv[buf ^ 1][1][swp8]) = rV;
    }
    if (T + 2 < 16) {
      rK = *reinterpret_cast<const u16x8*>(&Kb[(T + 2) * 4096 + p * 8]);
      rV = *reinterpret_cast<const u16x8*>(&Vb[(T + 2) * 1024 + vsrc0]);
    }

    bf16x8 kf[2][2];
    #pragma unroll
    for (int sn = 0; sn < 2; sn++) {
      kf[sn][0] = *reinterpret_cast<const bf16x8*>(&kv[buf][0][koff[sn]]);
      kf[sn][1] = *reinterpret_cast<const bf16x8*>(&kv[buf][0][koff[sn] + 512]);
    }
    f32x4 sc[2];
    __builtin_amdgcn_s_setprio(1);
    #pragma unroll
    for (int sn = 0; sn < 2; sn++) {
      f32x4 t = __builtin_amdgcn_mfma_f32_16x16x32_bf16(kf[sn][0], aq0, f32x4{0.f, 0.f, 0.f, 0.f}, 0, 0, 0);
      sc[sn] = __builtin_amdgcn_mfma_f32_16x16x32_bf16(kf[sn][1], aq1, t, 0, 0, 0);
    }
    __builtin_amdgcn_s_setprio(0);

    bf16x8 bv[4];
    #pragma unroll
    for (int cn = 0; cn < 4; cn++)
      bv[cn] = *reinterpret_cast<const bf16x8*>(&kv[buf][1][cn * 1024 + voffb]);

    // ---- lane-local softmax (one query), defer-rescale (T13) ----
    float mx = fmaxf(hmax4(sc[0]), hmax4(sc[1])) * SC2;
    mx = fmaxf(mx, __shfl_xor(mx, 16));
    mx = fmaxf(mx, __shfl_xor(mx, 32));
    if (!__all(mx <= mrow + 8.f)) {
      const float mn = fmaxf(mrow, mx);
      const float rsc = exp2f(mrow - mn);
      mrow = mn;
      lrow *= rsc;
      #pragma unroll
      for (int cn = 0; cn < 4; cn++)
        #pragma unroll
        for (int r = 0; r < 4; r++) opv[cn][r] *= rsc;
    }

    float e[8];
    float rs = 0.f;
    #pragma unroll
    for (int sn = 0; sn < 2; sn++)
      #pragma unroll
      for (int r = 0; r < 4; r++) {
        e[sn * 4 + r] = exp2f(fmaf(sc[sn][r], SC2, -mrow));
        rs += e[sn * 4 + r];
      }
    lrow += rs;

    union U8 { unsigned int u[4]; bf16x8 v; } a;
    a.u[0] = pk2(e[0], e[1]); a.u[1] = pk2(e[2], e[3]);
    a.u[2] = pk2(e[4], e[5]); a.u[3] = pk2(e[6], e[7]);
    const bf16x8 pb = a.v;

    __builtin_amdgcn_s_setprio(1);
    #pragma unroll
    for (int cn = 0; cn < 4; cn++)
      opv[cn] = __builtin_amdgcn_mfma_f32_16x16x32_bf16(bv[cn], pb, opv[cn], 0, 0, 0);
    __builtin_amdgcn_s_setprio(0);
  }

  float lt = lrow;
  lt += __shfl_xor(lt, 16);
  lt += __shfl_xor(lt, 32);

  // ---- all kv reads complete before aliased mrg writes ----
  __syncthreads();
  if (sh == 1) {
    float* m = mrg[qg][lane];
    m[0] = mrow;
    m[1] = lt;
    #pragma unroll
    for (int cn = 0; cn < 4; cn++)
      #pragma unroll
      for (int r = 0; r < 4; r++)
        m[2 + cn * 4 + r] = opv[cn][r];
  }
  __syncthreads();
  if (sh == 0) {
    const float* m = mrg[qg][lane];
    const float m2 = m[0], l2 = m[1];
    const float mf = fmaxf(mrow, m2);
    const float s1 = exp2f(mrow - mf);
    const float s2 = exp2f(m2 - mf);
    const float linv = 1.f / (lt * s1 + l2 * s2);
    unsigned short* dst = avP + (size_t)b * 524288;
    #pragma unroll
    for (int cn = 0; cn < 4; cn++) {
      const float* o2 = &m[2 + cn * 4];
      ushort4 o;
      o.x = f2us((opv[cn][0] * s1 + o2[0] * s2) * linv);
      o.y = f2us((opv[cn][1] * s1 + o2[1] * s2) * linv);
      o.z = f2us((opv[cn][2] * s1 + o2[2] * s2) * linv);
      o.w = f2us((opv[cn][3] * s1 + o2[3] * s2) * linv);
      *reinterpret_cast<ushort4*>(&dst[((size_t)(rt * 32 + hh * 4 + cn) << 8) + lg * 64 + lr * 4]) = o;
    }
  }
}

extern "C" void kernel_launch(void* const* d_in, const int* in_sizes, int n_in,
                              void* d_out, int out_size, void* d_ws, size_t ws_size,
                              hipStream_t stream) {
  const float* x      = (const float*)d_in[0];
  const float* gn_w   = (const float*)d_in[1];
  const float* gn_b   = (const float*)d_in[2];
  const float* qkv_w  = (const float*)d_in[3];
  const float* qkv_b  = (const float*)d_in[4];
  const float* proj_w = (const float*)d_in[5];
  const float* proj_b = (const float*)d_in[6];
  float* out = (float*)d_out;

  const size_t HT = (size_t)BBB * TTT * CCH;
  const size_t QK = (size_t)BBB * NHEAD * TTT * CHD;
  unsigned short* hP  = (unsigned short*)d_ws;
  unsigned short* vP  = hP + HT;
  unsigned short* avP = vP + QK;
  unsigned short* wq  = avP + HT;
  unsigned short* wp  = wq + (size_t)O_QKV * CCH;
  unsigned short* qPd = (unsigned short*)d_out;   // scratch in d_out (rewritten)
  unsigned short* kPd = qPd + QK;

  const int nslot = (O_QKV + CCH) * CCH / 4;
  wpack_kernel<<<dim3(nslot / 256), 256, 0, stream>>>(qkv_w, proj_w, wq, nslot);
  gn_kernel<<<dim3(BBB * NGRP), 256, 0, stream>>>(x, gn_w, gn_b, hP);
  gemm_p<0><<<dim3(TTT / 128, O_QKV / 128, BBB), 256, 0, stream>>>(
      wq, hP, qkv_b, nullptr, qPd, kPd, vP, nullptr, O_QKV);
  attn_p<<<dim3(1024), 512, 0, stream>>>(qPd, kPd, vP, avP);
  gemm_p<1><<<dim3(TTT / 128, CCH / 128, BBB), 256, 0, stream>>>(
      wp, avP, proj_b, x, nullptr, nullptr, nullptr, out, CCH);
}

// Round 18
// 87.455 us; speedup vs baseline: 1.1016x; 1.1016x over previous
//
#include <hip/hip_runtime.h>
#include <hip/hip_bf16.h>

#define CCH 512
#define TTT 1024
#define BBB 8
#define NGRP 32
#define CPG 16
#define NHEAD 8
#define CHD 64
#define O_QKV 1536

typedef __attribute__((ext_vector_type(8))) short bf16x8;
typedef __attribute__((ext_vector_type(4))) short s16x4;
typedef __attribute__((ext_vector_type(8))) unsigned short u16x8;
typedef __attribute__((ext_vector_type(4))) float f32x4;

__device__ __forceinline__ float us2f(unsigned short u) {
  union { unsigned int i; float f; } p; p.i = ((unsigned int)u) << 16; return p.f;
}
__device__ __forceinline__ unsigned short f2us(float f) {
  __hip_bfloat16 b = __float2bfloat16(f);
  return *reinterpret_cast<unsigned short*>(&b);
}
__device__ __forceinline__ bf16x8 cat8(s16x4 a, s16x4 b) {
  bf16x8 r;
  r[0] = a[0]; r[1] = a[1]; r[2] = a[2]; r[3] = a[3];
  r[4] = b[0]; r[5] = b[1]; r[6] = b[2]; r[7] = b[3];
  return r;
}
__device__ __forceinline__ float hmax4(f32x4 v) {
  return fmaxf(fmaxf(v[0], v[1]), fmaxf(v[2], v[3]));
}
__device__ __forceinline__ unsigned int pk2(float lo, float hi) {
  return ((unsigned int)f2us(hi) << 16) | (unsigned int)f2us(lo);
}

// OLD packed layout (hP, W, avP): subtile base (rt*(K/16)+kt)*256,
// within: ((k%16)/4)*64 + (row%16)*4 + (k%4).
// PL2 layout (qP, kP, vP): same subtile order, within row-major:
// (row%16)*16 + (k%16). Frag = ONE b128.

// ---------------- fused prep: bid<256 -> GroupNorm (1024 thr, 16 waves/CU);
//                  bid>=256 -> W f32->bf16 pack (1024 slots/block) ----------------
__global__ __launch_bounds__(1024) void prep_kernel(
    const float* __restrict__ x,
    const float* __restrict__ gw,
    const float* __restrict__ gb,
    unsigned short* __restrict__ hP,
    const float* __restrict__ wqf,
    const float* __restrict__ wpf,
    unsigned short* __restrict__ op,
    int nslot)
{
  __shared__ __align__(16) float xs[16][1028];
  __shared__ float red[34];
  const int tid = threadIdx.x;
  const int bidx = blockIdx.x;

  if (bidx >= 256) {
    // ---- wpack part (no barriers) ----
    const int s = (bidx - 256) * 1024 + tid;
    if (s < nslot) {
      const int u = s & 63, sub = s >> 6;
      const int kt = sub & 31, rt = sub >> 5;
      const int lg = u >> 4, lr = u & 15;
      const int row = rt * 16 + lr;
      const float* src = (row < O_QKV) ? &wqf[(size_t)row * CCH]
                                       : &wpf[(size_t)(row - O_QKV) * CCH];
      float4 v = *reinterpret_cast<const float4*>(&src[kt * 16 + lg * 4]);
      ushort4 r;
      r.x = f2us(v.x); r.y = f2us(v.y); r.z = f2us(v.z); r.w = f2us(v.w);
      reinterpret_cast<ushort4*>(op)[s] = r;
    }
    return;
  }

  // ---- GroupNorm part ----
  const int bb = bidx >> 5, g = bidx & 31;
  const size_t base = ((size_t)bb * CCH + (size_t)g * CPG) * TTT;
  const float4* xv = reinterpret_cast<const float4*>(x + base);

  float s = 0.f, q = 0.f;
  for (int i = tid; i < 4096; i += 1024) {
    float4 u = xv[i];
    const int c = i >> 8, t4 = (i & 255) << 2;
    *reinterpret_cast<float4*>(&xs[c][t4]) = u;
    s += (u.x + u.y) + (u.z + u.w);
    q += u.x * u.x + u.y * u.y + u.z * u.z + u.w * u.w;
  }
  #pragma unroll
  for (int off = 32; off > 0; off >>= 1) {
    s += __shfl_down(s, off);
    q += __shfl_down(q, off);
  }
  const int wid = tid >> 6, lane = tid & 63;
  if (lane == 0) { red[wid] = s; red[16 + wid] = q; }
  __syncthreads();
  if (tid == 0) {
    float S = 0.f, Q = 0.f;
    #pragma unroll
    for (int i = 0; i < 16; i++) { S += red[i]; Q += red[16 + i]; }
    float mu = S * (1.f / 16384.f);
    float var = Q * (1.f / 16384.f) - mu * mu;
    red[32] = mu;
    red[33] = rsqrtf(var + 1e-5f);
  }
  __syncthreads();
  const float mu = red[32], rstd = red[33];
  float wsc[16], wbs[16];
  #pragma unroll
  for (int cc = 0; cc < 16; cc++) {
    wsc[cc] = gw[g * CPG + cc] * rstd;
    wbs[cc] = gb[g * CPG + cc] - mu * wsc[cc];
  }
  {
    const int tt = tid;                      // one t per thread (1024 threads)
    float v[16];
    #pragma unroll
    for (int cc = 0; cc < 16; cc++)
      v[cc] = fmaf(xs[cc][tt], wsc[cc], wbs[cc]);
    unsigned short* dst = &hP[(size_t)bb * 524288 + ((size_t)((tt >> 4) * 32 + g)) * 256 + (tt & 15) * 4];
    #pragma unroll
    for (int l2 = 0; l2 < 4; l2++) {
      ushort4 st;
      st.x = f2us(v[l2 * 4 + 0]);
      st.y = f2us(v[l2 * 4 + 1]);
      st.z = f2us(v[l2 * 4 + 2]);
      st.w = f2us(v[l2 * 4 + 3]);
      *reinterpret_cast<ushort4*>(&dst[l2 * 64]) = st;
    }
  }
}

// ---------------- LDS-free packed MFMA GEMM, reg-dbuf K loop ----------------
template<int MODE>
__global__ __launch_bounds__(256) void gemm_p(
    const unsigned short* __restrict__ Ap,
    const unsigned short* __restrict__ Bp,
    const float* __restrict__ bias,
    const float* __restrict__ resid,
    unsigned short* __restrict__ oq,
    unsigned short* __restrict__ ok,
    unsigned short* __restrict__ ov,
    float* __restrict__ of,
    const int O)
{
  const int tid = threadIdx.x;
  const int bz = blockIdx.z, o0 = blockIdx.y << 7, t0 = blockIdx.x << 7;
  const int lane = tid & 63, w = tid >> 6;
  const int lg = lane >> 4, lr = lane & 15;
  const int wr = w >> 1, wc = w & 1;
  const int laneoff = (lg >> 1) * 256 + (lg & 1) * 128 + lr * 4;

  const unsigned short* Ab = Ap + (size_t)(((o0 >> 4) + wr * 4) * 32) * 256 + laneoff;
  const unsigned short* Bb = Bp + (size_t)bz * 524288
      + (size_t)(((t0 >> 4) + wc * 4) * 32) * 256 + laneoff;

  f32x4 acc[4][4];
  #pragma unroll
  for (int m = 0; m < 4; m++)
    #pragma unroll
    for (int n = 0; n < 4; n++) acc[m][n] = f32x4{0.f, 0.f, 0.f, 0.f};

#define LOADSET(af_, bf_, kb_) do {                                        \
    _Pragma("unroll") for (int m_ = 0; m_ < 4; m_++) {                     \
      const unsigned short* p_ = Ab + (m_ * 32 + (kb_)) * 256;             \
      af_[m_] = cat8(*reinterpret_cast<const s16x4*>(p_),                  \
                     *reinterpret_cast<const s16x4*>(p_ + 64));            \
    }                                                                      \
    _Pragma("unroll") for (int n_ = 0; n_ < 4; n_++) {                     \
      const unsigned short* p_ = Bb + (n_ * 32 + (kb_)) * 256;             \
      bf_[n_] = cat8(*reinterpret_cast<const s16x4*>(p_),                  \
                     *reinterpret_cast<const s16x4*>(p_ + 64));            \
    } } while (0)

#define MFMASET(af_, bf_) do {                                             \
    __builtin_amdgcn_s_setprio(1);                                         \
    _Pragma("unroll") for (int n_ = 0; n_ < 4; n_++)                       \
      _Pragma("unroll") for (int m_ = 0; m_ < 4; m_++)                     \
        acc[m_][n_] = __builtin_amdgcn_mfma_f32_16x16x32_bf16(             \
            af_[m_], bf_[n_], acc[m_][n_], 0, 0, 0);                       \
    __builtin_amdgcn_s_setprio(0); } while (0)

  bf16x8 afA[4], bfA[4], afB[4], bfB[4];
  LOADSET(afA, bfA, 0);
  #pragma unroll
  for (int kb = 0; kb < 32; kb += 4) {
    LOADSET(afB, bfB, kb + 2);          // prefetch next half-step
    MFMASET(afA, bfA);
    if (kb + 4 < 32) LOADSET(afA, bfA, kb + 4);
    MFMASET(afB, bfB);
  }
#undef LOADSET
#undef MFMASET

  if (MODE == 0) {
    const int a = (o0 >> 6) + wr;
    float bi[4][4];
    #pragma unroll
    for (int m = 0; m < 4; m++)
      #pragma unroll
      for (int r = 0; r < 4; r++)
        bi[m][r] = bias[a * 64 + m * 16 + lg * 4 + r];
    const int head = a / 3, part = a - head * 3;
    const size_t bho = ((size_t)bz * NHEAD + head) << 16;
    if (part < 2) {
      unsigned short* dst = (part == 0 ? oq : ok) + bho;
      #pragma unroll
      for (int n = 0; n < 4; n++) {
        const int rt = (t0 >> 4) + wc * 4 + n;
        #pragma unroll
        for (int m = 0; m < 4; m++) {
          ushort4 st;
          st.x = f2us(acc[m][n][0] + bi[m][0]);
          st.y = f2us(acc[m][n][1] + bi[m][1]);
          st.z = f2us(acc[m][n][2] + bi[m][2]);
          st.w = f2us(acc[m][n][3] + bi[m][3]);
          *reinterpret_cast<ushort4*>(&dst[(size_t)(rt * 4 + m) * 256 + lr * 16 + lg * 4]) = st;
        }
      }
    } else {
      unsigned short* dst = ov + bho;
      #pragma unroll
      for (int m = 0; m < 4; m++)
        #pragma unroll
        for (int n = 0; n < 4; n++) {
          const int kt = (t0 >> 4) + wc * 4 + n;
          unsigned short* q = &dst[(size_t)(m * 64 + kt) * 256 + lr];
          #pragma unroll
          for (int r = 0; r < 4; r++)
            q[(lg * 4 + r) * 16] = f2us(acc[m][n][r] + bi[m][r]);
        }
    }
  } else {
    #pragma unroll
    for (int m = 0; m < 4; m++)
      #pragma unroll
      for (int r = 0; r < 4; r++) {
        const int o = o0 + wr * 64 + m * 16 + lg * 4 + r;
        const float bv = bias[o];
        const size_t rowbase = ((size_t)bz * O + o) * TTT + t0 + wc * 64 + lr;
        #pragma unroll
        for (int n = 0; n < 4; n++) {
          const size_t idx = rowbase + n * 16;
          of[idx] = acc[m][n][r] + bv + resid[idx];
        }
      }
  }
}

// ---------------- LDS-staged flash attention (R15-exact: 32q/wave x 32s-half) ----------------
__global__ __launch_bounds__(512, 3) void attn_p(
    const unsigned short* __restrict__ qP,
    const unsigned short* __restrict__ kP,
    const unsigned short* __restrict__ vP,
    unsigned short* __restrict__ avP)
{
  const int bid = blockIdx.x;                    // 0..511
  const int bh = (bid & 7) * 8 + (bid >> 6);     // XCD-bijective
  const int t0 = ((bid >> 3) & 7) << 7;          // 128-query block
  const int b = bh >> 3, hh = bh & 7;
  const int tid = threadIdx.x;
  const int lane = tid & 63, w = tid >> 6;       // 8 waves
  const int qg = w & 3, sh = w >> 2;             // query-group, s-half
  const int lg = lane >> 4, lr = lane & 15;

  // kv (32 KB, main loop) and mrg (37.9 KB, epilogue only) alias one buffer.
  __shared__ __align__(16) unsigned char smem[4 * 64 * 37 * 4];  // 37888 B
  unsigned short (*kv)[2][4096] = reinterpret_cast<unsigned short (*)[2][4096]>(smem);
  float (*mrg)[64][37] = reinterpret_cast<float (*)[64][37]>(smem);

  const unsigned short* Qb = qP + ((size_t)bh << 16);
  const unsigned short* Kb = kP + ((size_t)bh << 16);
  const unsigned short* Vb = vP + ((size_t)bh << 16);

  const int p = tid;
  const int swp8 = (p ^ ((p >> 4) & 1)) * 8;
  const int vsrc0 = ((p >> 7) * 64 + ((p >> 5) & 3)) * 256 + (p & 31) * 8;

  const int PLOFF = (lg >> 1) * 256 + lr * 16 + (lg & 1) * 8;
  const int hK = (lg & 1) ^ ((lr >> 2) & 1);
  const int hV = (lg & 1) ^ ((lr >> 3) & 1);
  int koff[2];
  #pragma unroll
  for (int sn = 0; sn < 2; sn++) {
    const int srow4 = (sh * 2 + (lr >> 3)) * 4 + (lg >> 1);
    const int row16 = ((lr >> 2) & 1) * 8 + sn * 4 + (lr & 3);
    koff[sn] = srow4 * 256 + row16 * 16 + hK * 8;
  }
  const int voffb = (sh * 2 + (lg >> 1)) * 256 + lr * 16 + hV * 8;

  const int rt0 = (t0 >> 4) + qg * 2;
  bf16x8 aq[2][2];
  #pragma unroll
  for (int qs = 0; qs < 2; qs++) {
    aq[qs][0] = *reinterpret_cast<const bf16x8*>(&Qb[(rt0 + qs) * 1024 + PLOFF]);
    aq[qs][1] = *reinterpret_cast<const bf16x8*>(&Qb[(rt0 + qs) * 1024 + 512 + PLOFF]);
  }

  f32x4 opv[2][4];
  #pragma unroll
  for (int qs = 0; qs < 2; qs++)
    #pragma unroll
    for (int cn = 0; cn < 4; cn++) opv[qs][cn] = f32x4{0.f, 0.f, 0.f, 0.f};
  float mrow[2] = {-1e30f, -1e30f}, lrow[2] = {0.f, 0.f};
  const float SC2 = 0.125f * 1.44269504f;

  u16x8 rK = *reinterpret_cast<const u16x8*>(&Kb[p * 8]);
  u16x8 rV = *reinterpret_cast<const u16x8*>(&Vb[vsrc0]);
  *reinterpret_cast<u16x8*>(&kv[0][0][swp8]) = rK;
  *reinterpret_cast<u16x8*>(&kv[0][1][swp8]) = rV;
  rK = *reinterpret_cast<const u16x8*>(&Kb[4096 + p * 8]);
  rV = *reinterpret_cast<const u16x8*>(&Vb[1024 + vsrc0]);

  for (int T = 0; T < 16; T++) {
    const int buf = T & 1;
    __syncthreads();
    if (T + 1 < 16) {
      *reinterpret_cast<u16x8*>(&kv[buf ^ 1][0][swp8]) = rK;
      *reinterpret_cast<u16x8*>(&kv[buf ^ 1][1][swp8]) = rV;
    }
    if (T + 2 < 16) {
      rK = *reinterpret_cast<const u16x8*>(&Kb[(T + 2) * 4096 + p * 8]);
      rV = *reinterpret_cast<const u16x8*>(&Vb[(T + 2) * 1024 + vsrc0]);
    }

    bf16x8 kf[2][2];
    #pragma unroll
    for (int sn = 0; sn < 2; sn++) {
      kf[sn][0] = *reinterpret_cast<const bf16x8*>(&kv[buf][0][koff[sn]]);
      kf[sn][1] = *reinterpret_cast<const bf16x8*>(&kv[buf][0][koff[sn] + 512]);
    }
    f32x4 sc[2][2];
    __builtin_amdgcn_s_setprio(1);
    #pragma unroll
    for (int qs = 0; qs < 2; qs++)
      #pragma unroll
      for (int sn = 0; sn < 2; sn++) {
        f32x4 t = __builtin_amdgcn_mfma_f32_16x16x32_bf16(kf[sn][0], aq[qs][0], f32x4{0.f, 0.f, 0.f, 0.f}, 0, 0, 0);
        sc[qs][sn] = __builtin_amdgcn_mfma_f32_16x16x32_bf16(kf[sn][1], aq[qs][1], t, 0, 0, 0);
      }
    __builtin_amdgcn_s_setprio(0);

    bf16x8 bv[4];
    #pragma unroll
    for (int cn = 0; cn < 4; cn++)
      bv[cn] = *reinterpret_cast<const bf16x8*>(&kv[buf][1][cn * 1024 + voffb]);

    float mx[2];
    #pragma unroll
    for (int qs = 0; qs < 2; qs++) {
      float m_ = fmaxf(hmax4(sc[qs][0]), hmax4(sc[qs][1])) * SC2;
      m_ = fmaxf(m_, __shfl_xor(m_, 16));
      mx[qs] = fmaxf(m_, __shfl_xor(m_, 32));
    }
    if (!__all(mx[0] <= mrow[0] + 8.f && mx[1] <= mrow[1] + 8.f)) {
      #pragma unroll
      for (int qs = 0; qs < 2; qs++) {
        const float mn = fmaxf(mrow[qs], mx[qs]);
        const float rsc = exp2f(mrow[qs] - mn);
        mrow[qs] = mn;
        lrow[qs] *= rsc;
        #pragma unroll
        for (int cn = 0; cn < 4; cn++)
          #pragma unroll
          for (int r = 0; r < 4; r++) opv[qs][cn][r] *= rsc;
      }
    }

    bf16x8 pb[2];
    #pragma unroll
    for (int qs = 0; qs < 2; qs++) {
      float e[8];
      float rs = 0.f;
      #pragma unroll
      for (int sn = 0; sn < 2; sn++)
        #pragma unroll
        for (int r = 0; r < 4; r++) {
          e[sn * 4 + r] = exp2f(fmaf(sc[qs][sn][r], SC2, -mrow[qs]));
          rs += e[sn * 4 + r];
        }
      lrow[qs] += rs;
      union U8 { unsigned int u[4]; bf16x8 v; } a;
      a.u[0] = pk2(e[0], e[1]); a.u[1] = pk2(e[2], e[3]);
      a.u[2] = pk2(e[4], e[5]); a.u[3] = pk2(e[6], e[7]);
      pb[qs] = a.v;
    }

    __builtin_amdgcn_s_setprio(1);
    #pragma unroll
    for (int qs = 0; qs < 2; qs++)
      #pragma unroll
      for (int cn = 0; cn < 4; cn++)
        opv[qs][cn] = __builtin_amdgcn_mfma_f32_16x16x32_bf16(bv[cn], pb[qs], opv[qs][cn], 0, 0, 0);
    __builtin_amdgcn_s_setprio(0);
  }

  float lt[2];
  #pragma unroll
  for (int qs = 0; qs < 2; qs++) {
    float v = lrow[qs];
    v += __shfl_xor(v, 16);
    v += __shfl_xor(v, 32);
    lt[qs] = v;
  }

  // ---- all kv reads complete before aliased mrg writes ----
  __syncthreads();
  if (sh == 1) {
    float* m = mrg[qg][lane];
    m[0] = mrow[0]; m[1] = mrow[1];
    m[2] = lt[0];   m[3] = lt[1];
    #pragma unroll
    for (int qs = 0; qs < 2; qs++)
      #pragma unroll
      for (int cn = 0; cn < 4; cn++)
        #pragma unroll
        for (int r = 0; r < 4; r++)
          m[4 + qs * 16 + cn * 4 + r] = opv[qs][cn][r];
  }
  __syncthreads();
  if (sh == 0) {
    const float* m = mrg[qg][lane];
    unsigned short* dst = avP + (size_t)b * 524288;
    #pragma unroll
    for (int qs = 0; qs < 2; qs++) {
      const float m2 = m[qs], l2 = m[2 + qs];
      const float mf = fmaxf(mrow[qs], m2);
      const float s1 = exp2f(mrow[qs] - mf);
      const float s2 = exp2f(m2 - mf);
      const float linv = 1.f / (lt[qs] * s1 + l2 * s2);
      const int rt = rt0 + qs;
      #pragma unroll
      for (int cn = 0; cn < 4; cn++) {
        const float* o2 = &m[4 + qs * 16 + cn * 4];
        ushort4 o;
        o.x = f2us((opv[qs][cn][0] * s1 + o2[0] * s2) * linv);
        o.y = f2us((opv[qs][cn][1] * s1 + o2[1] * s2) * linv);
        o.z = f2us((opv[qs][cn][2] * s1 + o2[2] * s2) * linv);
        o.w = f2us((opv[qs][cn][3] * s1 + o2[3] * s2) * linv);
        *reinterpret_cast<ushort4*>(&dst[((size_t)(rt * 32 + hh * 4 + cn) << 8) + lg * 64 + lr * 4]) = o;
      }
    }
  }
}

extern "C" void kernel_launch(void* const* d_in, const int* in_sizes, int n_in,
                              void* d_out, int out_size, void* d_ws, size_t ws_size,
                              hipStream_t stream) {
  const float* x      = (const float*)d_in[0];
  const float* gn_w   = (const float*)d_in[1];
  const float* gn_b   = (const float*)d_in[2];
  const float* qkv_w  = (const float*)d_in[3];
  const float* qkv_b  = (const float*)d_in[4];
  const float* proj_w = (const float*)d_in[5];
  const float* proj_b = (const float*)d_in[6];
  float* out = (float*)d_out;

  const size_t HT = (size_t)BBB * TTT * CCH;
  const size_t QK = (size_t)BBB * NHEAD * TTT * CHD;
  unsigned short* hP  = (unsigned short*)d_ws;
  unsigned short* vP  = hP + HT;
  unsigned short* avP = vP + QK;
  unsigned short* wq  = avP + HT;
  unsigned short* wp  = wq + (size_t)O_QKV * CCH;
  unsigned short* qPd = (unsigned short*)d_out;   // scratch in d_out (rewritten)
  unsigned short* kPd = qPd + QK;

  const int nslot = (O_QKV + CCH) * CCH / 4;      // 262144 = 256 * 1024
  prep_kernel<<<dim3(512), 1024, 0, stream>>>(x, gn_w, gn_b, hP, qkv_w, proj_w, wq, nslot);
  gemm_p<0><<<dim3(TTT / 128, O_QKV / 128, BBB), 256, 0, stream>>>(
      wq, hP, qkv_b, nullptr, qPd, kPd, vP, nullptr, O_QKV);
  attn_p<<<dim3(512), 512, 0, stream>>>(qPd, kPd, vP, avP);
  gemm_p<1><<<dim3(TTT / 128, CCH / 128, BBB), 256, 0, stream>>>(
      wp, avP, proj_b, x, nullptr, nullptr, nullptr, out, CCH);
}

// Round 19
// 76.716 us; speedup vs baseline: 1.2558x; 1.1400x over previous
//
#include <hip/hip_runtime.h>
#include <hip/hip_bf16.h>

#define CCH 512
#define TTT 1024
#define BBB 8
#define NGRP 32
#define CPG 16
#define NHEAD 8
#define CHD 64
#define O_QKV 1536

typedef __attribute__((ext_vector_type(8))) short bf16x8;
typedef __attribute__((ext_vector_type(4))) short s16x4;
typedef __attribute__((ext_vector_type(8))) unsigned short u16x8;
typedef __attribute__((ext_vector_type(4))) float f32x4;

__device__ __forceinline__ float us2f(unsigned short u) {
  union { unsigned int i; float f; } p; p.i = ((unsigned int)u) << 16; return p.f;
}
__device__ __forceinline__ unsigned short f2us(float f) {
  __hip_bfloat16 b = __float2bfloat16(f);
  return *reinterpret_cast<unsigned short*>(&b);
}
__device__ __forceinline__ float hmax4(f32x4 v) {
  return fmaxf(fmaxf(v[0], v[1]), fmaxf(v[2], v[3]));
}
__device__ __forceinline__ unsigned int pk2(float lo, float hi) {
  return ((unsigned int)f2us(hi) << 16) | (unsigned int)f2us(lo);
}

// PL2 layout (ALL packed operands now: W, hP, qP, kP, vP, avP):
// logical [R rows][K cols] bf16; subtile (rt=row/16, kt=k/16),
// base = (rt*(K/16)+kt)*256, within = (row%16)*16 + (k%16).
// MFMA A/B frag (row, k0=half*32+lg*8) = ONE b128 at
//   base(rt, half*2+(lg>>1))*256 + lr*16 + (lg&1)*8.

// ---------------- fused prep: bid<256 -> GroupNorm (1024 thr);
//                  bid>=256 -> W f32->bf16 PL2 pack ----------------
__global__ __launch_bounds__(1024) void prep_kernel(
    const float* __restrict__ x,
    const float* __restrict__ gw,
    const float* __restrict__ gb,
    unsigned short* __restrict__ hP,
    const float* __restrict__ wqf,
    const float* __restrict__ wpf,
    unsigned short* __restrict__ op,
    int nslot)
{
  __shared__ __align__(16) float xs[16][1028];
  __shared__ float red[34];
  const int tid = threadIdx.x;
  const int bidx = blockIdx.x;

  if (bidx >= 256) {
    // ---- wpack part (PL2, no barriers) ----
    const int s = (bidx - 256) * 1024 + tid;
    if (s < nslot) {
      const int u = s & 63, sub = s >> 6;
      const int kt = sub & 31, rt = sub >> 5;
      const int lg = u >> 4, lr = u & 15;
      const int row = rt * 16 + lr;
      const float* src = (row < O_QKV) ? &wqf[(size_t)row * CCH]
                                       : &wpf[(size_t)(row - O_QKV) * CCH];
      float4 v = *reinterpret_cast<const float4*>(&src[kt * 16 + lg * 4]);
      ushort4 r;
      r.x = f2us(v.x); r.y = f2us(v.y); r.z = f2us(v.z); r.w = f2us(v.w);
      *reinterpret_cast<ushort4*>(&op[(size_t)sub * 256 + lr * 16 + lg * 4]) = r;
    }
    return;
  }

  // ---- GroupNorm part ----
  const int bb = bidx >> 5, g = bidx & 31;
  const size_t base = ((size_t)bb * CCH + (size_t)g * CPG) * TTT;
  const float4* xv = reinterpret_cast<const float4*>(x + base);

  float s = 0.f, q = 0.f;
  for (int i = tid; i < 4096; i += 1024) {
    float4 u = xv[i];
    const int c = i >> 8, t4 = (i & 255) << 2;
    *reinterpret_cast<float4*>(&xs[c][t4]) = u;
    s += (u.x + u.y) + (u.z + u.w);
    q += u.x * u.x + u.y * u.y + u.z * u.z + u.w * u.w;
  }
  #pragma unroll
  for (int off = 32; off > 0; off >>= 1) {
    s += __shfl_down(s, off);
    q += __shfl_down(q, off);
  }
  const int wid = tid >> 6, lane = tid & 63;
  if (lane == 0) { red[wid] = s; red[16 + wid] = q; }
  __syncthreads();
  if (tid == 0) {
    float S = 0.f, Q = 0.f;
    #pragma unroll
    for (int i = 0; i < 16; i++) { S += red[i]; Q += red[16 + i]; }
    float mu = S * (1.f / 16384.f);
    float var = Q * (1.f / 16384.f) - mu * mu;
    red[32] = mu;
    red[33] = rsqrtf(var + 1e-5f);
  }
  __syncthreads();
  const float mu = red[32], rstd = red[33];
  float wsc[16], wbs[16];
  #pragma unroll
  for (int cc = 0; cc < 16; cc++) {
    wsc[cc] = gw[g * CPG + cc] * rstd;
    wbs[cc] = gb[g * CPG + cc] - mu * wsc[cc];
  }
  {
    const int tt = tid;                      // one t per thread
    float v[16];
    #pragma unroll
    for (int cc = 0; cc < 16; cc++)
      v[cc] = fmaf(xs[cc][tt], wsc[cc], wbs[cc]);
    // PL2: within = (t%16)*16 + c -> 16 contiguous shorts = two 16B stores
    unsigned short* dst = &hP[(size_t)bb * 524288 + ((size_t)((tt >> 4) * 32 + g)) * 256 + (tt & 15) * 16];
    u16x8 st0, st1;
    #pragma unroll
    for (int cc = 0; cc < 8; cc++) { st0[cc] = f2us(v[cc]); st1[cc] = f2us(v[cc + 8]); }
    *reinterpret_cast<u16x8*>(dst) = st0;
    *reinterpret_cast<u16x8*>(dst + 8) = st1;
  }
}

// ---------------- LDS-free PL2 MFMA GEMM, reg-dbuf K loop, 1 b128/frag ----------------
template<int MODE>
__global__ __launch_bounds__(256) void gemm_p(
    const unsigned short* __restrict__ Ap,
    const unsigned short* __restrict__ Bp,
    const float* __restrict__ bias,
    const float* __restrict__ resid,
    unsigned short* __restrict__ oq,
    unsigned short* __restrict__ ok,
    unsigned short* __restrict__ ov,
    float* __restrict__ of,
    const int O)
{
  const int tid = threadIdx.x;
  const int bz = blockIdx.z, o0 = blockIdx.y << 7, t0 = blockIdx.x << 7;
  const int lane = tid & 63, w = tid >> 6;
  const int lg = lane >> 4, lr = lane & 15;
  const int wr = w >> 1, wc = w & 1;
  const int laneoff = (lg >> 1) * 256 + lr * 16 + (lg & 1) * 8;   // PL2 frag

  const unsigned short* Ab = Ap + (size_t)(((o0 >> 4) + wr * 4) * 32) * 256 + laneoff;
  const unsigned short* Bb = Bp + (size_t)bz * 524288
      + (size_t)(((t0 >> 4) + wc * 4) * 32) * 256 + laneoff;

  f32x4 acc[4][4];
  #pragma unroll
  for (int m = 0; m < 4; m++)
    #pragma unroll
    for (int n = 0; n < 4; n++) acc[m][n] = f32x4{0.f, 0.f, 0.f, 0.f};

#define LOADSET(af_, bf_, kb_) do {                                        \
    _Pragma("unroll") for (int m_ = 0; m_ < 4; m_++)                       \
      af_[m_] = *reinterpret_cast<const bf16x8*>(Ab + (m_ * 32 + (kb_)) * 256); \
    _Pragma("unroll") for (int n_ = 0; n_ < 4; n_++)                       \
      bf_[n_] = *reinterpret_cast<const bf16x8*>(Bb + (n_ * 32 + (kb_)) * 256); \
    } while (0)

#define MFMASET(af_, bf_) do {                                             \
    __builtin_amdgcn_s_setprio(1);                                         \
    _Pragma("unroll") for (int n_ = 0; n_ < 4; n_++)                       \
      _Pragma("unroll") for (int m_ = 0; m_ < 4; m_++)                     \
        acc[m_][n_] = __builtin_amdgcn_mfma_f32_16x16x32_bf16(             \
            af_[m_], bf_[n_], acc[m_][n_], 0, 0, 0);                       \
    __builtin_amdgcn_s_setprio(0); } while (0)

  bf16x8 afA[4], bfA[4], afB[4], bfB[4];
  LOADSET(afA, bfA, 0);
  #pragma unroll
  for (int kb = 0; kb < 32; kb += 4) {
    LOADSET(afB, bfB, kb + 2);          // prefetch next half-step
    MFMASET(afA, bfA);
    if (kb + 4 < 32) LOADSET(afA, bfA, kb + 4);
    MFMASET(afB, bfB);
  }
#undef LOADSET
#undef MFMASET

  if (MODE == 0) {
    const int a = (o0 >> 6) + wr;
    float bi[4][4];
    #pragma unroll
    for (int m = 0; m < 4; m++)
      #pragma unroll
      for (int r = 0; r < 4; r++)
        bi[m][r] = bias[a * 64 + m * 16 + lg * 4 + r];
    const int head = a / 3, part = a - head * 3;
    const size_t bho = ((size_t)bz * NHEAD + head) << 16;
    if (part < 2) {
      unsigned short* dst = (part == 0 ? oq : ok) + bho;
      #pragma unroll
      for (int n = 0; n < 4; n++) {
        const int rt = (t0 >> 4) + wc * 4 + n;
        #pragma unroll
        for (int m = 0; m < 4; m++) {
          ushort4 st;
          st.x = f2us(acc[m][n][0] + bi[m][0]);
          st.y = f2us(acc[m][n][1] + bi[m][1]);
          st.z = f2us(acc[m][n][2] + bi[m][2]);
          st.w = f2us(acc[m][n][3] + bi[m][3]);
          *reinterpret_cast<ushort4*>(&dst[(size_t)(rt * 4 + m) * 256 + lr * 16 + lg * 4]) = st;
        }
      }
    } else {
      unsigned short* dst = ov + bho;
      #pragma unroll
      for (int m = 0; m < 4; m++)
        #pragma unroll
        for (int n = 0; n < 4; n++) {
          const int kt = (t0 >> 4) + wc * 4 + n;
          unsigned short* q = &dst[(size_t)(m * 64 + kt) * 256 + lr];
          #pragma unroll
          for (int r = 0; r < 4; r++)
            q[(lg * 4 + r) * 16] = f2us(acc[m][n][r] + bi[m][r]);
        }
    }
  } else {
    #pragma unroll
    for (int m = 0; m < 4; m++)
      #pragma unroll
      for (int r = 0; r < 4; r++) {
        const int o = o0 + wr * 64 + m * 16 + lg * 4 + r;
        const float bv = bias[o];
        const size_t rowbase = ((size_t)bz * O + o) * TTT + t0 + wc * 64 + lr;
        #pragma unroll
        for (int n = 0; n < 4; n++) {
          const size_t idx = rowbase + n * 16;
          of[idx] = acc[m][n][r] + bv + resid[idx];
        }
      }
  }
}

// ---------------- LDS-staged flash attention (R15 structure; avP write -> PL2) ----------------
__global__ __launch_bounds__(512, 3) void attn_p(
    const unsigned short* __restrict__ qP,
    const unsigned short* __restrict__ kP,
    const unsigned short* __restrict__ vP,
    unsigned short* __restrict__ avP)
{
  const int bid = blockIdx.x;                    // 0..511
  const int bh = (bid & 7) * 8 + (bid >> 6);     // XCD-bijective
  const int t0 = ((bid >> 3) & 7) << 7;          // 128-query block
  const int b = bh >> 3, hh = bh & 7;
  const int tid = threadIdx.x;
  const int lane = tid & 63, w = tid >> 6;       // 8 waves
  const int qg = w & 3, sh = w >> 2;             // query-group, s-half
  const int lg = lane >> 4, lr = lane & 15;

  // kv (32 KB, main loop) and mrg (37.9 KB, epilogue only) alias one buffer.
  __shared__ __align__(16) unsigned char smem[4 * 64 * 37 * 4];  // 37888 B
  unsigned short (*kv)[2][4096] = reinterpret_cast<unsigned short (*)[2][4096]>(smem);
  float (*mrg)[64][37] = reinterpret_cast<float (*)[64][37]>(smem);

  const unsigned short* Qb = qP + ((size_t)bh << 16);
  const unsigned short* Kb = kP + ((size_t)bh << 16);
  const unsigned short* Vb = vP + ((size_t)bh << 16);

  const int p = tid;
  const int swp8 = (p ^ ((p >> 4) & 1)) * 8;
  const int vsrc0 = ((p >> 7) * 64 + ((p >> 5) & 3)) * 256 + (p & 31) * 8;

  const int PLOFF = (lg >> 1) * 256 + lr * 16 + (lg & 1) * 8;
  const int hK = (lg & 1) ^ ((lr >> 2) & 1);
  const int hV = (lg & 1) ^ ((lr >> 3) & 1);
  int koff[2];
  #pragma unroll
  for (int sn = 0; sn < 2; sn++) {
    const int srow4 = (sh * 2 + (lr >> 3)) * 4 + (lg >> 1);
    const int row16 = ((lr >> 2) & 1) * 8 + sn * 4 + (lr & 3);
    koff[sn] = srow4 * 256 + row16 * 16 + hK * 8;
  }
  const int voffb = (sh * 2 + (lg >> 1)) * 256 + lr * 16 + hV * 8;

  const int rt0 = (t0 >> 4) + qg * 2;
  bf16x8 aq[2][2];
  #pragma unroll
  for (int qs = 0; qs < 2; qs++) {
    aq[qs][0] = *reinterpret_cast<const bf16x8*>(&Qb[(rt0 + qs) * 1024 + PLOFF]);
    aq[qs][1] = *reinterpret_cast<const bf16x8*>(&Qb[(rt0 + qs) * 1024 + 512 + PLOFF]);
  }

  f32x4 opv[2][4];
  #pragma unroll
  for (int qs = 0; qs < 2; qs++)
    #pragma unroll
    for (int cn = 0; cn < 4; cn++) opv[qs][cn] = f32x4{0.f, 0.f, 0.f, 0.f};
  float mrow[2] = {-1e30f, -1e30f}, lrow[2] = {0.f, 0.f};
  const float SC2 = 0.125f * 1.44269504f;

  u16x8 rK = *reinterpret_cast<const u16x8*>(&Kb[p * 8]);
  u16x8 rV = *reinterpret_cast<const u16x8*>(&Vb[vsrc0]);
  *reinterpret_cast<u16x8*>(&kv[0][0][swp8]) = rK;
  *reinterpret_cast<u16x8*>(&kv[0][1][swp8]) = rV;
  rK = *reinterpret_cast<const u16x8*>(&Kb[4096 + p * 8]);
  rV = *reinterpret_cast<const u16x8*>(&Vb[1024 + vsrc0]);

  for (int T = 0; T < 16; T++) {
    const int buf = T & 1;
    __syncthreads();
    if (T + 1 < 16) {
      *reinterpret_cast<u16x8*>(&kv[buf ^ 1][0][swp8]) = rK;
      *reinterpret_cast<u16x8*>(&kv[buf ^ 1][1][swp8]) = rV;
    }
    if (T + 2 < 16) {
      rK = *reinterpret_cast<const u16x8*>(&Kb[(T + 2) * 4096 + p * 8]);
      rV = *reinterpret_cast<const u16x8*>(&Vb[(T + 2) * 1024 + vsrc0]);
    }

    bf16x8 kf[2][2];
    #pragma unroll
    for (int sn = 0; sn < 2; sn++) {
      kf[sn][0] = *reinterpret_cast<const bf16x8*>(&kv[buf][0][koff[sn]]);
      kf[sn][1] = *reinterpret_cast<const bf16x8*>(&kv[buf][0][koff[sn] + 512]);
    }
    f32x4 sc[2][2];
    __builtin_amdgcn_s_setprio(1);
    #pragma unroll
    for (int qs = 0; qs < 2; qs++)
      #pragma unroll
      for (int sn = 0; sn < 2; sn++) {
        f32x4 t = __builtin_amdgcn_mfma_f32_16x16x32_bf16(kf[sn][0], aq[qs][0], f32x4{0.f, 0.f, 0.f, 0.f}, 0, 0, 0);
        sc[qs][sn] = __builtin_amdgcn_mfma_f32_16x16x32_bf16(kf[sn][1], aq[qs][1], t, 0, 0, 0);
      }
    __builtin_amdgcn_s_setprio(0);

    bf16x8 bv[4];
    #pragma unroll
    for (int cn = 0; cn < 4; cn++)
      bv[cn] = *reinterpret_cast<const bf16x8*>(&kv[buf][1][cn * 1024 + voffb]);

    float mx[2];
    #pragma unroll
    for (int qs = 0; qs < 2; qs++) {
      float m_ = fmaxf(hmax4(sc[qs][0]), hmax4(sc[qs][1])) * SC2;
      m_ = fmaxf(m_, __shfl_xor(m_, 16));
      mx[qs] = fmaxf(m_, __shfl_xor(m_, 32));
    }
    if (!__all(mx[0] <= mrow[0] + 8.f && mx[1] <= mrow[1] + 8.f)) {
      #pragma unroll
      for (int qs = 0; qs < 2; qs++) {
        const float mn = fmaxf(mrow[qs], mx[qs]);
        const float rsc = exp2f(mrow[qs] - mn);
        mrow[qs] = mn;
        lrow[qs] *= rsc;
        #pragma unroll
        for (int cn = 0; cn < 4; cn++)
          #pragma unroll
          for (int r = 0; r < 4; r++) opv[qs][cn][r] *= rsc;
      }
    }

    bf16x8 pb[2];
    #pragma unroll
    for (int qs = 0; qs < 2; qs++) {
      float e[8];
      float rs = 0.f;
      #pragma unroll
      for (int sn = 0; sn < 2; sn++)
        #pragma unroll
        for (int r = 0; r < 4; r++) {
          e[sn * 4 + r] = exp2f(fmaf(sc[qs][sn][r], SC2, -mrow[qs]));
          rs += e[sn * 4 + r];
        }
      lrow[qs] += rs;
      union U8 { unsigned int u[4]; bf16x8 v; } a;
      a.u[0] = pk2(e[0], e[1]); a.u[1] = pk2(e[2], e[3]);
      a.u[2] = pk2(e[4], e[5]); a.u[3] = pk2(e[6], e[7]);
      pb[qs] = a.v;
    }

    __builtin_amdgcn_s_setprio(1);
    #pragma unroll
    for (int qs = 0; qs < 2; qs++)
      #pragma unroll
      for (int cn = 0; cn < 4; cn++)
        opv[qs][cn] = __builtin_amdgcn_mfma_f32_16x16x32_bf16(bv[cn], pb[qs], opv[qs][cn], 0, 0, 0);
    __builtin_amdgcn_s_setprio(0);
  }

  float lt[2];
  #pragma unroll
  for (int qs = 0; qs < 2; qs++) {
    float v = lrow[qs];
    v += __shfl_xor(v, 16);
    v += __shfl_xor(v, 32);
    lt[qs] = v;
  }

  // ---- all kv reads complete before aliased mrg writes ----
  __syncthreads();
  if (sh == 1) {
    float* m = mrg[qg][lane];
    m[0] = mrow[0]; m[1] = mrow[1];
    m[2] = lt[0];   m[3] = lt[1];
    #pragma unroll
    for (int qs = 0; qs < 2; qs++)
      #pragma unroll
      for (int cn = 0; cn < 4; cn++)
        #pragma unroll
        for (int r = 0; r < 4; r++)
          m[4 + qs * 16 + cn * 4 + r] = opv[qs][cn][r];
  }
  __syncthreads();
  if (sh == 0) {
    const float* m = mrg[qg][lane];
    unsigned short* dst = avP + (size_t)b * 524288;
    #pragma unroll
    for (int qs = 0; qs < 2; qs++) {
      const float m2 = m[qs], l2 = m[2 + qs];
      const float mf = fmaxf(mrow[qs], m2);
      const float s1 = exp2f(mrow[qs] - mf);
      const float s2 = exp2f(m2 - mf);
      const float linv = 1.f / (lt[qs] * s1 + l2 * s2);
      const int rt = rt0 + qs;
      #pragma unroll
      for (int cn = 0; cn < 4; cn++) {
        const float* o2 = &m[4 + qs * 16 + cn * 4];
        ushort4 o;
        o.x = f2us((opv[qs][cn][0] * s1 + o2[0] * s2) * linv);
        o.y = f2us((opv[qs][cn][1] * s1 + o2[1] * s2) * linv);
        o.z = f2us((opv[qs][cn][2] * s1 + o2[2] * s2) * linv);
        o.w = f2us((opv[qs][cn][3] * s1 + o2[3] * s2) * linv);
        // PL2: within = (t%16)*16 + c%16
        *reinterpret_cast<ushort4*>(&dst[((size_t)(rt * 32 + hh * 4 + cn) << 8) + lr * 16 + lg * 4]) = o;
      }
    }
  }
}

extern "C" void kernel_launch(void* const* d_in, const int* in_sizes, int n_in,
                              void* d_out, int out_size, void* d_ws, size_t ws_size,
                              hipStream_t stream) {
  const float* x      = (const float*)d_in[0];
  const float* gn_w   = (const float*)d_in[1];
  const float* gn_b   = (const float*)d_in[2];
  const float* qkv_w  = (const float*)d_in[3];
  const float* qkv_b  = (const float*)d_in[4];
  const float* proj_w = (const float*)d_in[5];
  const float* proj_b = (const float*)d_in[6];
  float* out = (float*)d_out;

  const size_t HT = (size_t)BBB * TTT * CCH;
  const size_t QK = (size_t)BBB * NHEAD * TTT * CHD;
  unsigned short* hP  = (unsigned short*)d_ws;
  unsigned short* vP  = hP + HT;
  unsigned short* avP = vP + QK;
  unsigned short* wq  = avP + HT;
  unsigned short* wp  = wq + (size_t)O_QKV * CCH;
  unsigned short* qPd = (unsigned short*)d_out;   // scratch in d_out (rewritten)
  unsigned short* kPd = qPd + QK;

  const int nslot = (O_QKV + CCH) * CCH / 4;      // 262144 = 256 * 1024
  prep_kernel<<<dim3(512), 1024, 0, stream>>>(x, gn_w, gn_b, hP, qkv_w, proj_w, wq, nslot);
  gemm_p<0><<<dim3(TTT / 128, O_QKV / 128, BBB), 256, 0, stream>>>(
      wq, hP, qkv_b, nullptr, qPd, kPd, vP, nullptr, O_QKV);
  attn_p<<<dim3(512), 512, 0, stream>>>(qPd, kPd, vP, avP);
  gemm_p<1><<<dim3(TTT / 128, CCH / 128, BBB), 256, 0, stream>>>(
      wp, avP, proj_b, x, nullptr, nullptr, nullptr, out, CCH);
}